// Round 3
// baseline (735.346 us; speedup 1.0000x reference)
//
#include <hip/hip_runtime.h>

#define NR_  2048
#define ND_  2048
#define NCM_ 32
#define NT_  256
#define VPT_ 8   // ND_ / NT_

__device__ __forceinline__ float softplus_f(float a) {
    // numerically stable softplus: max(a,0) + log1p(exp(-|a|))
    return fmaxf(a, 0.0f) + log1pf(expf(-fabsf(a)));
}

__global__ __launch_bounds__(NT_) void rwm_kernel(
    const float* __restrict__ CM_Alpha,
    const float* __restrict__ Wearing_Alpha,
    const float* __restrict__ Mobility_Alpha,
    const float* __restrict__ RegionR,
    const float* __restrict__ GI_mean,
    const float* __restrict__ GI_sd,
    const float* __restrict__ InitialSize_log,
    const float* __restrict__ noise,
    const float* __restrict__ psi,
    const float* __restrict__ NPIs,
    const float* __restrict__ wearing,
    const float* __restrict__ mobility,
    float* __restrict__ out)
{
    __shared__ float sAlpha[NCM_];
    __shared__ float sWave[NT_ / 64];

    const int r = blockIdx.x;
    const int t = threadIdx.x;
    if (t < NCM_) sAlpha[t] = CM_Alpha[t];
    __syncthreads();

    const int d0 = t * VPT_;

    // uniform scalars
    const float gim = GI_mean[0];
    const float gis = GI_sd[0];
    const float gi_beta = expf(gim / (gis * gis));
    const float inv_gi_alpha = (gis * gis) / (gim * gim);
    const float wA = Wearing_Alpha[0];
    const float mA = Mobility_Alpha[0];
    const float rr = RegionR[r];
    const float rp = expf(psi[0]);
    const float LOG2F_ = 0.6931471805599453f;

    // mobility reduction at d=0 for this row (broadcast load)
    const float a0 = mA * mobility[(size_t)r * ND_];
    const float grm0 = softplus_f(a0) - LOG2F_;

    // ---- einsum over c: acc[j] = sum_c alpha[c] * NPIs[r,c,d0+j] ----
    float acc[VPT_];
    #pragma unroll
    for (int j = 0; j < VPT_; ++j) acc[j] = 0.0f;

    const float* nbase = NPIs + ((size_t)r * NCM_) * ND_ + d0;
    #pragma unroll 8
    for (int c = 0; c < NCM_; ++c) {
        const float al = sAlpha[c];
        const float4 v0 = *reinterpret_cast<const float4*>(nbase + (size_t)c * ND_);
        const float4 v1 = *reinterpret_cast<const float4*>(nbase + (size_t)c * ND_ + 4);
        acc[0] = fmaf(al, v0.x, acc[0]);
        acc[1] = fmaf(al, v0.y, acc[1]);
        acc[2] = fmaf(al, v0.z, acc[2]);
        acc[3] = fmaf(al, v0.w, acc[3]);
        acc[4] = fmaf(al, v1.x, acc[4]);
        acc[5] = fmaf(al, v1.y, acc[5]);
        acc[6] = fmaf(al, v1.z, acc[6]);
        acc[7] = fmaf(al, v1.w, acc[7]);
    }

    // ---- pointwise: ExpectedGrowth + noise ----
    const size_t row = (size_t)r * ND_ + d0;
    const float4 w0 = *reinterpret_cast<const float4*>(wearing + row);
    const float4 w1 = *reinterpret_cast<const float4*>(wearing + row + 4);
    const float4 m0 = *reinterpret_cast<const float4*>(mobility + row);
    const float4 m1 = *reinterpret_cast<const float4*>(mobility + row + 4);
    const float4 n0 = *reinterpret_cast<const float4*>(noise + row);
    const float4 n1 = *reinterpret_cast<const float4*>(noise + row + 4);
    const float wv[VPT_] = {w0.x, w0.y, w0.z, w0.w, w1.x, w1.y, w1.z, w1.w};
    const float mv[VPT_] = {m0.x, m0.y, m0.z, m0.w, m1.x, m1.y, m1.z, m1.w};
    const float nv[VPT_] = {n0.x, n0.y, n0.z, n0.w, n1.x, n1.y, n1.z, n1.w};

    float g[VPT_];
    #pragma unroll
    for (int j = 0; j < VPT_; ++j) {
        const float a = mA * mv[j];
        const float grm = softplus_f(a) - LOG2F_;
        const float elr = rr - acc[j] - wA * wv[j] - (grm - grm0);
        const float eg = gi_beta + expf(elr) * inv_gi_alpha;
        g[j] = eg + nv[j];
    }

    // ---- intra-thread inclusive scan ----
    #pragma unroll
    for (int j = 1; j < VPT_; ++j) g[j] += g[j - 1];

    // ---- block-wide exclusive scan of per-thread totals ----
    const int lane = t & 63;
    const int wid  = t >> 6;
    const float tot = g[VPT_ - 1];
    float x = tot;
    #pragma unroll
    for (int o = 1; o < 64; o <<= 1) {
        const float y = __shfl_up(x, o);
        if (lane >= o) x += y;
    }
    if (lane == 63) sWave[wid] = x;
    __syncthreads();
    float off = 0.0f;
    #pragma unroll
    for (int w = 0; w < NT_ / 64; ++w) off += (w < wid) ? sWave[w] : 0.0f;
    const float excl = off + (x - tot);

    // ---- epilogue: Log_Infected -> p ----
    const float base = InitialSize_log[r] + excl;
    float o8[VPT_];
    #pragma unroll
    for (int j = 0; j < VPT_; ++j) {
        const float li = base + g[j];
        const float infv = expf(li);
        o8[j] = rp / (rp + infv) + 1e-8f;
    }
    float4* op = reinterpret_cast<float4*>(out + row);
    op[0] = make_float4(o8[0], o8[1], o8[2], o8[3]);
    op[1] = make_float4(o8[4], o8[5], o8[6], o8[7]);
}

extern "C" void kernel_launch(void* const* d_in, const int* in_sizes, int n_in,
                              void* d_out, int out_size, void* d_ws, size_t ws_size,
                              hipStream_t stream) {
    const float* CM_Alpha        = (const float*)d_in[0];
    const float* Wearing_Alpha   = (const float*)d_in[1];
    const float* Mobility_Alpha  = (const float*)d_in[2];
    const float* RegionR         = (const float*)d_in[3];
    const float* GI_mean         = (const float*)d_in[4];
    const float* GI_sd           = (const float*)d_in[5];
    const float* InitialSize_log = (const float*)d_in[6];
    const float* noise           = (const float*)d_in[7];
    const float* psi             = (const float*)d_in[8];
    const float* NPIs            = (const float*)d_in[9];
    const float* wearing         = (const float*)d_in[10];
    const float* mobility        = (const float*)d_in[11];
    float* out = (float*)d_out;

    rwm_kernel<<<NR_, NT_, 0, stream>>>(CM_Alpha, Wearing_Alpha, Mobility_Alpha,
                                        RegionR, GI_mean, GI_sd, InitialSize_log,
                                        noise, psi, NPIs, wearing, mobility, out);
}

// Round 6
// 720.824 us; speedup vs baseline: 1.0201x; 1.0201x over previous
//
#include <hip/hip_runtime.h>

#define NR_  2048
#define ND_  2048
#define NCM_ 32
#define NT_  512
#define VPT_ 4    // ND_ / NT_
#define NW_  (NT_ / 64)

__device__ __forceinline__ float softplus_f(float a) {
    // numerically stable softplus: max(a,0) + log1p(exp(-|a|))
    return fmaxf(a, 0.0f) + log1pf(expf(-fabsf(a)));
}

__global__ __launch_bounds__(NT_) void rwm_kernel(
    const float* __restrict__ CM_Alpha,
    const float* __restrict__ Wearing_Alpha,
    const float* __restrict__ Mobility_Alpha,
    const float* __restrict__ RegionR,
    const float* __restrict__ GI_mean,
    const float* __restrict__ GI_sd,
    const float* __restrict__ InitialSize_log,
    const float* __restrict__ noise,
    const float* __restrict__ psi,
    const float* __restrict__ NPIs,
    const float* __restrict__ wearing,
    const float* __restrict__ mobility,
    float* __restrict__ out)
{
    __shared__ float sAlpha[NCM_];
    __shared__ float sWave[NW_];

    const int r = blockIdx.x;
    const int t = threadIdx.x;
    if (t < NCM_) sAlpha[t] = CM_Alpha[t];
    __syncthreads();

    const int d0 = t * VPT_;   // each thread: one dense float4 at d0

    // uniform scalars
    const float gim = GI_mean[0];
    const float gis = GI_sd[0];
    const float gi_beta = expf(gim / (gis * gis));
    const float inv_gi_alpha = (gis * gis) / (gim * gim);
    const float wA = Wearing_Alpha[0];
    const float mA = Mobility_Alpha[0];
    const float rr = RegionR[r];
    const float rp = expf(psi[0]);
    const float LOG2F_ = 0.6931471805599453f;

    // mobility reduction at d=0 for this row (broadcast load)
    const float a0 = mA * mobility[(size_t)r * ND_];
    const float grm0 = softplus_f(a0) - LOG2F_;

    // ---- einsum over c: acc[j] = sum_c alpha[c] * NPIs[r,c,d0+j] ----
    // Every load instruction is lane-dense: 64 lanes x 16B = 1KB contiguous.
    float4 acc = make_float4(0.f, 0.f, 0.f, 0.f);
    const float* nbase = NPIs + ((size_t)r * NCM_) * ND_ + d0;
    #pragma unroll 8
    for (int c = 0; c < NCM_; ++c) {
        const float al = sAlpha[c];
        const float4 v = *reinterpret_cast<const float4*>(nbase + (size_t)c * ND_);
        acc.x = fmaf(al, v.x, acc.x);
        acc.y = fmaf(al, v.y, acc.y);
        acc.z = fmaf(al, v.z, acc.z);
        acc.w = fmaf(al, v.w, acc.w);
    }

    // ---- pointwise: ExpectedGrowth + noise ----
    const size_t row = (size_t)r * ND_ + d0;
    const float4 w4 = *reinterpret_cast<const float4*>(wearing + row);
    const float4 m4 = *reinterpret_cast<const float4*>(mobility + row);
    const float4 n4 = *reinterpret_cast<const float4*>(noise + row);
    const float av[VPT_] = {acc.x, acc.y, acc.z, acc.w};
    const float wv[VPT_] = {w4.x, w4.y, w4.z, w4.w};
    const float mv[VPT_] = {m4.x, m4.y, m4.z, m4.w};
    const float nv[VPT_] = {n4.x, n4.y, n4.z, n4.w};

    float g[VPT_];
    #pragma unroll
    for (int j = 0; j < VPT_; ++j) {
        const float a = mA * mv[j];
        const float grm = softplus_f(a) - LOG2F_;
        const float elr = rr - av[j] - wA * wv[j] - (grm - grm0);
        const float eg = gi_beta + expf(elr) * inv_gi_alpha;
        g[j] = eg + nv[j];
    }

    // ---- intra-thread inclusive scan (4) ----
    #pragma unroll
    for (int j = 1; j < VPT_; ++j) g[j] += g[j - 1];

    // ---- block-wide exclusive scan of per-thread totals ----
    const int lane = t & 63;
    const int wid  = t >> 6;
    const float tot = g[VPT_ - 1];
    float x = tot;
    #pragma unroll
    for (int o = 1; o < 64; o <<= 1) {
        const float y = __shfl_up(x, o);
        if (lane >= o) x += y;
    }
    if (lane == 63) sWave[wid] = x;
    __syncthreads();
    float off = 0.0f;
    #pragma unroll
    for (int w = 0; w < NW_; ++w) off += (w < wid) ? sWave[w] : 0.0f;
    const float excl = off + (x - tot);

    // ---- epilogue: Log_Infected -> p ----
    const float base = InitialSize_log[r] + excl;
    float4 o4;
    {
        const float li0 = base + g[0];
        const float li1 = base + g[1];
        const float li2 = base + g[2];
        const float li3 = base + g[3];
        o4.x = rp / (rp + expf(li0)) + 1e-8f;
        o4.y = rp / (rp + expf(li1)) + 1e-8f;
        o4.z = rp / (rp + expf(li2)) + 1e-8f;
        o4.w = rp / (rp + expf(li3)) + 1e-8f;
    }
    *reinterpret_cast<float4*>(out + row) = o4;
}

extern "C" void kernel_launch(void* const* d_in, const int* in_sizes, int n_in,
                              void* d_out, int out_size, void* d_ws, size_t ws_size,
                              hipStream_t stream) {
    const float* CM_Alpha        = (const float*)d_in[0];
    const float* Wearing_Alpha   = (const float*)d_in[1];
    const float* Mobility_Alpha  = (const float*)d_in[2];
    const float* RegionR         = (const float*)d_in[3];
    const float* GI_mean         = (const float*)d_in[4];
    const float* GI_sd           = (const float*)d_in[5];
    const float* InitialSize_log = (const float*)d_in[6];
    const float* noise           = (const float*)d_in[7];
    const float* psi             = (const float*)d_in[8];
    const float* NPIs            = (const float*)d_in[9];
    const float* wearing         = (const float*)d_in[10];
    const float* mobility        = (const float*)d_in[11];
    float* out = (float*)d_out;

    rwm_kernel<<<NR_, NT_, 0, stream>>>(CM_Alpha, Wearing_Alpha, Mobility_Alpha,
                                        RegionR, GI_mean, GI_sd, InitialSize_log,
                                        noise, psi, NPIs, wearing, mobility, out);
}

// Round 9
// 702.348 us; speedup vs baseline: 1.0470x; 1.0263x over previous
//
#include <hip/hip_runtime.h>

#define NR_  2048
#define ND_  2048
#define NCM_ 32
#define NT_  512
#define VPT_ 4    // ND_ / NT_
#define NW_  (NT_ / 64)

// native clang vector type: accepted by __builtin_nontemporal_load/store
typedef float f32x4 __attribute__((ext_vector_type(4)));

__device__ __forceinline__ float softplus_f(float a) {
    // numerically stable softplus: max(a,0) + log1p(exp(-|a|))
    return fmaxf(a, 0.0f) + log1pf(expf(-fabsf(a)));
}

__global__ __launch_bounds__(NT_) void rwm_kernel(
    const float* __restrict__ CM_Alpha,
    const float* __restrict__ Wearing_Alpha,
    const float* __restrict__ Mobility_Alpha,
    const float* __restrict__ RegionR,
    const float* __restrict__ GI_mean,
    const float* __restrict__ GI_sd,
    const float* __restrict__ InitialSize_log,
    const float* __restrict__ noise,
    const float* __restrict__ psi,
    const float* __restrict__ NPIs,
    const float* __restrict__ wearing,
    const float* __restrict__ mobility,
    float* __restrict__ out)
{
    __shared__ float sAlpha[NCM_];
    __shared__ float sWave[NW_];

    const int r = blockIdx.x;
    const int t = threadIdx.x;
    if (t < NCM_) sAlpha[t] = CM_Alpha[t];
    __syncthreads();

    const int d0 = t * VPT_;   // each thread: one dense float4 at d0

    // uniform scalars
    const float gim = GI_mean[0];
    const float gis = GI_sd[0];
    const float gi_beta = expf(gim / (gis * gis));
    const float inv_gi_alpha = (gis * gis) / (gim * gim);
    const float wA = Wearing_Alpha[0];
    const float mA = Mobility_Alpha[0];
    const float rr = RegionR[r];
    const float rp = expf(psi[0]);
    const float LOG2F_ = 0.6931471805599453f;

    // mobility reduction at d=0 for this row (broadcast load)
    const float a0 = mA * mobility[(size_t)r * ND_];
    const float grm0 = softplus_f(a0) - LOG2F_;

    // ---- einsum over c: acc[j] = sum_c alpha[c] * NPIs[r,c,d0+j] ----
    // Lane-dense 1KB/wave loads; non-temporal (zero reuse, don't evict
    // dirty poison-fill lines from L2/L3 -> avoid writeback contention).
    f32x4 acc = (f32x4){0.f, 0.f, 0.f, 0.f};
    const float* nbase = NPIs + ((size_t)r * NCM_) * ND_ + d0;
    #pragma unroll 8
    for (int c = 0; c < NCM_; ++c) {
        const float al = sAlpha[c];
        const f32x4 v = __builtin_nontemporal_load(
            reinterpret_cast<const f32x4*>(nbase + (size_t)c * ND_));
        acc.x = fmaf(al, v.x, acc.x);
        acc.y = fmaf(al, v.y, acc.y);
        acc.z = fmaf(al, v.z, acc.z);
        acc.w = fmaf(al, v.w, acc.w);
    }

    // ---- pointwise: ExpectedGrowth + noise ----
    const size_t row = (size_t)r * ND_ + d0;
    const f32x4 w4 = __builtin_nontemporal_load(reinterpret_cast<const f32x4*>(wearing + row));
    const f32x4 m4 = __builtin_nontemporal_load(reinterpret_cast<const f32x4*>(mobility + row));
    const f32x4 n4 = __builtin_nontemporal_load(reinterpret_cast<const f32x4*>(noise + row));
    const float av[VPT_] = {acc.x, acc.y, acc.z, acc.w};
    const float wv[VPT_] = {w4.x, w4.y, w4.z, w4.w};
    const float mv[VPT_] = {m4.x, m4.y, m4.z, m4.w};
    const float nv[VPT_] = {n4.x, n4.y, n4.z, n4.w};

    float g[VPT_];
    #pragma unroll
    for (int j = 0; j < VPT_; ++j) {
        const float a = mA * mv[j];
        const float grm = softplus_f(a) - LOG2F_;
        const float elr = rr - av[j] - wA * wv[j] - (grm - grm0);
        const float eg = gi_beta + expf(elr) * inv_gi_alpha;
        g[j] = eg + nv[j];
    }

    // ---- intra-thread inclusive scan (4) ----
    #pragma unroll
    for (int j = 1; j < VPT_; ++j) g[j] += g[j - 1];

    // ---- block-wide exclusive scan of per-thread totals ----
    const int lane = t & 63;
    const int wid  = t >> 6;
    const float tot = g[VPT_ - 1];
    float x = tot;
    #pragma unroll
    for (int o = 1; o < 64; o <<= 1) {
        const float y = __shfl_up(x, o);
        if (lane >= o) x += y;
    }
    if (lane == 63) sWave[wid] = x;
    __syncthreads();
    float off = 0.0f;
    #pragma unroll
    for (int w = 0; w < NW_; ++w) off += (w < wid) ? sWave[w] : 0.0f;
    const float excl = off + (x - tot);

    // ---- epilogue: Log_Infected -> p ----
    const float base = InitialSize_log[r] + excl;
    f32x4 o4;
    {
        const float li0 = base + g[0];
        const float li1 = base + g[1];
        const float li2 = base + g[2];
        const float li3 = base + g[3];
        o4.x = rp / (rp + expf(li0)) + 1e-8f;
        o4.y = rp / (rp + expf(li1)) + 1e-8f;
        o4.z = rp / (rp + expf(li2)) + 1e-8f;
        o4.w = rp / (rp + expf(li3)) + 1e-8f;
    }
    __builtin_nontemporal_store(o4, reinterpret_cast<f32x4*>(out + row));
}

extern "C" void kernel_launch(void* const* d_in, const int* in_sizes, int n_in,
                              void* d_out, int out_size, void* d_ws, size_t ws_size,
                              hipStream_t stream) {
    const float* CM_Alpha        = (const float*)d_in[0];
    const float* Wearing_Alpha   = (const float*)d_in[1];
    const float* Mobility_Alpha  = (const float*)d_in[2];
    const float* RegionR         = (const float*)d_in[3];
    const float* GI_mean         = (const float*)d_in[4];
    const float* GI_sd           = (const float*)d_in[5];
    const float* InitialSize_log = (const float*)d_in[6];
    const float* noise           = (const float*)d_in[7];
    const float* psi             = (const float*)d_in[8];
    const float* NPIs            = (const float*)d_in[9];
    const float* wearing         = (const float*)d_in[10];
    const float* mobility        = (const float*)d_in[11];
    float* out = (float*)d_out;

    rwm_kernel<<<NR_, NT_, 0, stream>>>(CM_Alpha, Wearing_Alpha, Mobility_Alpha,
                                        RegionR, GI_mean, GI_sd, InitialSize_log,
                                        noise, psi, NPIs, wearing, mobility, out);
}